// Round 1
// baseline (397.758 us; speedup 1.0000x reference)
//
#include <hip/hip_runtime.h>
#include <stdint.h>

#define SEQ  20
#define H1   128
#define H2   256
#define NCLS 100000

__device__ __forceinline__ float sigm(float x) { return 1.0f / (1.0f + __expf(-x)); }
__device__ __forceinline__ float tanhfast(float x) {
    float e = __expf(-2.0f * fabsf(x));
    float t = (1.0f - e) / (1.0f + e);
    return copysignf(t, x);
}

// Grid barrier across co-resident blocks: arrive (release) + spin (acquire).
// Counter zeroed by hipMemsetAsync before launch; targets are cumulative.
__device__ __forceinline__ void gbar(int* cnt, int target) {
    __syncthreads();
    if (threadIdx.x == 0) {
        __hip_atomic_fetch_add(cnt, 1, __ATOMIC_ACQ_REL, __HIP_MEMORY_SCOPE_AGENT);
        while (__hip_atomic_load(cnt, __ATOMIC_ACQUIRE, __HIP_MEMORY_SCOPE_AGENT) < target)
            __builtin_amdgcn_s_sleep(1);
    }
    __syncthreads();
}

// ---------------------------------------------------------------------------
// Layer-1 LSTM: ONE block per direction, ZERO device barriers.
// 512 threads = 512 gate rows; each thread holds its full 128-wide Whh row
// in VGPRs (128 regs; 512 thr = 2 waves/SIMD -> 256 VGPR budget).
// h lives in LDS; reads are wave-uniform (broadcast, conflict-free).
// ---------------------------------------------------------------------------
__global__ __launch_bounds__(512, 2) void k_l1r(
    const float* __restrict__ x,
    const float* __restrict__ h0f, const float* __restrict__ c0f,
    const float* __restrict__ h0b, const float* __restrict__ c0b,
    const float* __restrict__ WihF, const float* __restrict__ WhhF,
    const float* __restrict__ bihF, const float* __restrict__ bhhF,
    const float* __restrict__ WihB, const float* __restrict__ WhhB,
    const float* __restrict__ bihB, const float* __restrict__ bhhB,
    float* __restrict__ comb)      // [SEQ][H2]
{
    const int dir = blockIdx.x;    // 0 = fwd, 1 = bwd
    const float* Wih = dir ? WihB : WihF;
    const float* Whh = dir ? WhhB : WhhF;
    const float* bih = dir ? bihB : bihF;
    const float* bhh = dir ? bhhB : bhhF;
    const float* h0  = dir ? h0b  : h0f;
    const float* c0  = dir ? c0b  : c0f;

    __shared__ float xs[SEQ * H1];            // 10240 B
    __shared__ float hcur[H1];                //   512 B
    __shared__ float gv[4 * H1];              //  2048 B
    __shared__ float gxs[4 * H1][SEQ + 1];    // 43008 B (stride 21: coprime w/ 32 banks)

    const int tid = threadIdx.x;              // global gate row 0..511 (i|f|g|o x128)

    for (int i = tid; i < SEQ * H1; i += 512) xs[i] = x[i];
    if (tid < H1) hcur[tid] = h0[tid];
    float creg = (tid < H1) ? c0[tid] : 0.0f;
    const float bias = bih[tid] + bhh[tid];

    // Wih row -> registers (live range ends after prologue; reused for Whh)
    float w[H1];
    {
        const float* wr = Wih + tid * H1;
#pragma unroll
        for (int k = 0; k < H1; k += 4) {
            float4 v = *(const float4*)(wr + k);
            w[k] = v.x; w[k + 1] = v.y; w[k + 2] = v.z; w[k + 3] = v.w;
        }
    }
    __syncthreads();

    // ---- prologue: gxs[row][t] = bias + Wih[row]·x[t'] (no syncs needed:
    //      each thread writes/reads only its own gxs row) ----
    for (int t = 0; t < SEQ; ++t) {
        const float* xp = xs + (dir ? (SEQ - 1 - t) : t) * H1;
        float a0 = 0.f, a1 = 0.f, a2 = 0.f, a3 = 0.f;
#pragma unroll
        for (int k = 0; k < H1; k += 4) {
            float4 hv = *(const float4*)(xp + k);
            a0 += w[k] * hv.x; a1 += w[k + 1] * hv.y;
            a2 += w[k + 2] * hv.z; a3 += w[k + 3] * hv.w;
        }
        gxs[tid][t] = bias + ((a0 + a1) + (a2 + a3));
    }

    // Whh row -> registers
    {
        const float* wr = Whh + tid * H1;
#pragma unroll
        for (int k = 0; k < H1; k += 4) {
            float4 v = *(const float4*)(wr + k);
            w[k] = v.x; w[k + 1] = v.y; w[k + 2] = v.z; w[k + 3] = v.w;
        }
    }

    // ---- serial recurrence: only __syncthreads, no global traffic ----
    for (int t = 0; t < SEQ; ++t) {
        float a0 = 0.f, a1 = 0.f, a2 = 0.f, a3 = 0.f;
#pragma unroll
        for (int k = 0; k < H1; k += 4) {
            float4 hv = *(const float4*)(hcur + k);   // broadcast read
            a0 += w[k] * hv.x; a1 += w[k + 1] * hv.y;
            a2 += w[k + 2] * hv.z; a3 += w[k + 3] * hv.w;
        }
        gv[tid] = gxs[tid][t] + ((a0 + a1) + (a2 + a3));
        __syncthreads();
        if (tid < H1) {
            float gi = gv[tid], gf = gv[H1 + tid], gg = gv[2 * H1 + tid], go = gv[3 * H1 + tid];
            float cn = sigm(gf) * creg + sigm(gi) * tanhfast(gg);
            creg = cn;
            float hn = sigm(go) * tanhfast(cn);
            comb[t * H2 + dir * H1 + tid] = hn;
            hcur[tid] = hn;
        }
        __syncthreads();
    }
}

// ---------------------------------------------------------------------------
// Layer-2 LSTM: 4 blocks (was 32) x 512 threads. Block owns 64 cells
// (256 gate rows); thread owns a 128-col half-row of Whh_l in VGPRs.
// One 4-participant device barrier per step.
// ---------------------------------------------------------------------------
__global__ __launch_bounds__(512, 2) void k_l2r(
    const float* __restrict__ Whhl,
    const float* __restrict__ h0l, const float* __restrict__ c0l,
    const float* __restrict__ Wihl,
    const float* __restrict__ bihl, const float* __restrict__ bhhl,
    const float* __restrict__ comb,
    float* __restrict__ fb,        // [SEQ][H2]
    float* __restrict__ hg2,       // [H2] agent-scope exchange
    int* __restrict__ sync)
{
    const int b = blockIdx.x;                 // 0..3, cells [b*64, b*64+64)
    __shared__ float cs[SEQ * H2];            // 20480 B
    __shared__ float hcur[H2];                //  1024 B
    __shared__ float gv[4 * 64];              //  1024 B
    __shared__ float gxs[H2][SEQ + 1];        // 21504 B

    const int tid  = threadIdx.x;
    const int L    = tid >> 1;                // local gate row 0..255
    const int half = tid & 1;                 // column half (0: cols 0..127, 1: 128..255)
    const int R    = (L >> 6) * H2 + b * 64 + (L & 63);  // global gate row
    const float bias = bihl[R] + bhhl[R];

    for (int i = tid; i < SEQ * H2; i += 512) cs[i] = comb[i];
    if (tid < H2) hcur[tid] = h0l[tid];
    float creg = (tid < 64) ? c0l[b * 64 + tid] : 0.0f;

    // Wihl half-row -> registers (reused for Whhl after prologue)
    float w[H1];
    {
        const float* wr = Wihl + R * H2 + half * H1;
#pragma unroll
        for (int k = 0; k < H1; k += 4) {
            float4 v = *(const float4*)(wr + k);
            w[k] = v.x; w[k + 1] = v.y; w[k + 2] = v.z; w[k + 3] = v.w;
        }
    }
    __syncthreads();

    // ---- prologue: gxs[L][t] = bias + Wihl[R]·comb[t] ----
    for (int t = 0; t < SEQ; ++t) {
        const float* cp = cs + t * H2 + half * H1;
        float a0 = 0.f, a1 = 0.f, a2 = 0.f, a3 = 0.f;
#pragma unroll
        for (int k = 0; k < H1; k += 4) {
            float4 hv = *(const float4*)(cp + k);
            a0 += w[k] * hv.x; a1 += w[k + 1] * hv.y;
            a2 += w[k + 2] * hv.z; a3 += w[k + 3] * hv.w;
        }
        float a = (a0 + a1) + (a2 + a3);
        a += __shfl_xor(a, 1);                // pair (half 0/1) full-row sum
        if (half == 0) gxs[L][t] = bias + a;
    }

    // Whhl half-row -> registers
    {
        const float* wr = Whhl + R * H2 + half * H1;
#pragma unroll
        for (int k = 0; k < H1; k += 4) {
            float4 v = *(const float4*)(wr + k);
            w[k] = v.x; w[k + 1] = v.y; w[k + 2] = v.z; w[k + 3] = v.w;
        }
    }

    // ---- serial recurrence, one 4-block barrier per step ----
    for (int t = 0; t < SEQ; ++t) {
        const float* hp = hcur + half * H1;
        float a0 = 0.f, a1 = 0.f, a2 = 0.f, a3 = 0.f;
#pragma unroll
        for (int k = 0; k < H1; k += 4) {
            float4 hv = *(const float4*)(hp + k);
            a0 += w[k] * hv.x; a1 += w[k + 1] * hv.y;
            a2 += w[k + 2] * hv.z; a3 += w[k + 3] * hv.w;
        }
        float a = (a0 + a1) + (a2 + a3);
        a += __shfl_xor(a, 1);
        if (half == 0) gv[L] = gxs[L][t] + a;
        __syncthreads();
        if (tid < 64) {
            float gi = gv[tid], gf = gv[64 + tid], gg = gv[128 + tid], go = gv[192 + tid];
            float cn = sigm(gf) * creg + sigm(gi) * tanhfast(gg);
            creg = cn;
            float hn = sigm(go) * tanhfast(cn);
            fb[t * H2 + b * 64 + tid] = hn;
            __hip_atomic_store(&hg2[b * 64 + tid], hn,
                               __ATOMIC_RELEASE, __HIP_MEMORY_SCOPE_AGENT);
        }
        gbar(&sync[0], 4 * (t + 1));
        if (tid < H2)
            hcur[tid] = __hip_atomic_load(&hg2[tid],
                                          __ATOMIC_RELAXED, __HIP_MEMORY_SCOPE_AGENT);
        __syncthreads();
    }
}

// ---------------------------------------------------------------------------
// Output linear (unchanged). Thread = one class; fb transposed in LDS.
// ---------------------------------------------------------------------------
__global__ __launch_bounds__(256, 4) void k_out_v(
    const float* __restrict__ Wlin, const float* __restrict__ blin,
    const float* __restrict__ fb, float* __restrict__ out)
{
    __shared__ float fbs[H2][SEQ];
    const int tid = threadIdx.x;
    for (int t = 0; t < SEQ; ++t) fbs[tid][t] = fb[t * H2 + tid];
    __syncthreads();

    int n = blockIdx.x * 256 + tid;
    if (n >= NCLS) return;
    float acc[SEQ];
    float bv = blin[n];
#pragma unroll
    for (int t = 0; t < SEQ; ++t) acc[t] = bv;

    const float* wp = Wlin + (size_t)n * H2;
    for (int k = 0; k < H2; k += 4) {
        float4 wv = *(const float4*)(wp + k);
#pragma unroll
        for (int t = 0; t < SEQ; t += 4) {
            float4 f0 = *(const float4*)(&fbs[k][t]);
            float4 f1 = *(const float4*)(&fbs[k + 1][t]);
            float4 f2 = *(const float4*)(&fbs[k + 2][t]);
            float4 f3 = *(const float4*)(&fbs[k + 3][t]);
            acc[t]     += wv.x * f0.x + wv.y * f1.x + wv.z * f2.x + wv.w * f3.x;
            acc[t + 1] += wv.x * f0.y + wv.y * f1.y + wv.z * f2.y + wv.w * f3.y;
            acc[t + 2] += wv.x * f0.z + wv.y * f1.z + wv.z * f2.z + wv.w * f3.z;
            acc[t + 3] += wv.x * f0.w + wv.y * f1.w + wv.z * f2.w + wv.w * f3.w;
        }
    }
#pragma unroll
    for (int t = 0; t < SEQ; ++t)
        out[(size_t)t * NCLS + n] = acc[t];
}

// ---------------------------------------------------------------------------
extern "C" void kernel_launch(void* const* d_in, const int* in_sizes, int n_in,
                              void* d_out, int out_size, void* d_ws, size_t ws_size,
                              hipStream_t stream)
{
    const float* x    = (const float*)d_in[0];
    const float* h0f_ = (const float*)d_in[1];
    const float* c0f_ = (const float*)d_in[2];
    const float* h0b_ = (const float*)d_in[3];
    const float* c0b_ = (const float*)d_in[4];
    const float* h0l_ = (const float*)d_in[5];
    const float* c0l_ = (const float*)d_in[6];
    const float* WihF = (const float*)d_in[7];
    const float* WhhF = (const float*)d_in[8];
    const float* bihF = (const float*)d_in[9];
    const float* bhhF = (const float*)d_in[10];
    const float* WihB = (const float*)d_in[11];
    const float* WhhB = (const float*)d_in[12];
    const float* bihB = (const float*)d_in[13];
    const float* bhhB = (const float*)d_in[14];
    const float* Wihl = (const float*)d_in[15];
    const float* Whhl = (const float*)d_in[16];
    const float* bihl = (const float*)d_in[17];
    const float* bhhl = (const float*)d_in[18];
    const float* Wlin = (const float*)d_in[19];
    const float* blin = (const float*)d_in[20];

    char* ws = (char*)d_ws;
    int*   sync = (int*)ws;                      // counters (256 B reserved)
    float* hg2  = (float*)(ws + 1536);           // [256]
    float* comb = (float*)(ws + 4096);           // [20][256]
    float* fb   = (float*)(ws + 24576);          // [20][256]

    hipMemsetAsync(sync, 0, 256, stream);

    k_l1r<<<2, 512, 0, stream>>>(x, h0f_, c0f_, h0b_, c0b_,
                                 WihF, WhhF, bihF, bhhF,
                                 WihB, WhhB, bihB, bhhB,
                                 comb);
    k_l2r<<<4, 512, 0, stream>>>(Whhl, h0l_, c0l_,
                                 Wihl, bihl, bhhl,
                                 comb, fb, hg2, sync);
    k_out_v<<<391, 256, 0, stream>>>(Wlin, blin, fb, (float*)d_out);
}

// Round 2
// 354.288 us; speedup vs baseline: 1.1227x; 1.1227x over previous
//
#include <hip/hip_runtime.h>
#include <stdint.h>

#define SEQ  20
#define H1   128
#define H2   256
#define NCLS 100000

__device__ __forceinline__ float sigm(float x) { return 1.0f / (1.0f + __expf(-x)); }
__device__ __forceinline__ float tanhfast(float x) {
    float e = __expf(-2.0f * fabsf(x));
    float t = (1.0f - e) / (1.0f + e);
    return copysignf(t, x);
}

// ---------------------------------------------------------------------------
// Layer-1 LSTM: ONE block per direction (grid=2), 1024 threads, no device
// barriers. Thread = (col-group cg 0..3 [32 cols], row-pair rp 0..255).
// Weights: 2 rows x 32 cols = 16 float4 = 64 VGPRs per thread (fits the
// hard 128-VGPR cap at 16 waves/block; round-1 failure was a 128-float
// array spilling at that cap). cg in HIGH bits -> all lanes of a wave read
// the SAME hcur address (LDS broadcast, conflict-free).
// ---------------------------------------------------------------------------
__global__ __launch_bounds__(1024, 4) void k_l1(
    const float* __restrict__ x,
    const float* __restrict__ h0f, const float* __restrict__ c0f,
    const float* __restrict__ h0b, const float* __restrict__ c0b,
    const float* __restrict__ WihF, const float* __restrict__ WhhF,
    const float* __restrict__ bihF, const float* __restrict__ bhhF,
    const float* __restrict__ WihB, const float* __restrict__ WhhB,
    const float* __restrict__ bihB, const float* __restrict__ bhhB,
    float* __restrict__ comb)      // [SEQ][H2]
{
    const int dir = blockIdx.x;    // 0 = fwd, 1 = bwd
    const float* Wih = dir ? WihB : WihF;
    const float* Whh = dir ? WhhB : WhhF;
    const float* bih = dir ? bihB : bihF;
    const float* bhh = dir ? bhhB : bhhF;
    const float* h0  = dir ? h0b  : h0f;
    const float* c0  = dir ? c0b  : c0f;

    __shared__ float xs[SEQ * H1];            // 10240 B
    __shared__ float hcur[H1];                //   512 B
    __shared__ float biasL[4 * H1];           //  2048 B
    __shared__ float gxs[4 * H1][SEQ + 1];    // 43008 B (stride 21, coprime w/ 32)
    __shared__ float partial[4 * 520];        //  8320 B (stride 520 -> +8 banks/cg)

    const int tid = threadIdx.x;
    const int cg  = tid >> 8;                 // col group (32 cols), wave-uniform
    const int rp  = tid & 255;                // row pair
    const int r0  = rp * 2;                   // rows r0, r0+1 (0..511, i|f|g|o x128)

    for (int i = tid; i < SEQ * H1; i += 1024) xs[i] = x[i];
    if (tid < 4 * H1) biasL[tid] = bih[tid] + bhh[tid];
    if (tid < H1) hcur[tid] = h0[tid];
    float creg = (tid < H1) ? c0[tid] : 0.0f;

    // Wih slice -> registers (reused for Whh after prologue)
    float4 wa[8], wb[8];
    {
        const float4* pa = (const float4*)(Wih + r0 * H1 + cg * 32);
        const float4* pb = (const float4*)(Wih + (r0 + 1) * H1 + cg * 32);
#pragma unroll
        for (int j = 0; j < 8; ++j) { wa[j] = pa[j]; wb[j] = pb[j]; }
    }
    __syncthreads();

    // ---- prologue: gxs[r][t] = bias[r] + Wih[r]·x[t'] ----
    for (int t = 0; t < SEQ; ++t) {
        const float4* xp = (const float4*)(xs + (dir ? (SEQ - 1 - t) : t) * H1 + cg * 32);
        float a0 = 0.f, a1 = 0.f;
#pragma unroll
        for (int j = 0; j < 8; ++j) {
            float4 v = xp[j];
            a0 += wa[j].x * v.x + wa[j].y * v.y + wa[j].z * v.z + wa[j].w * v.w;
            a1 += wb[j].x * v.x + wb[j].y * v.y + wb[j].z * v.z + wb[j].w * v.w;
        }
        *(float2*)(partial + cg * 520 + r0) = make_float2(a0, a1);
        __syncthreads();
        if (tid < 4 * H1) {
            float s = biasL[tid] + partial[tid] + partial[520 + tid]
                    + partial[1040 + tid] + partial[1560 + tid];
            gxs[tid][t] = s;
        }
        __syncthreads();
    }

    // Whh slice -> registers
    {
        const float4* pa = (const float4*)(Whh + r0 * H1 + cg * 32);
        const float4* pb = (const float4*)(Whh + (r0 + 1) * H1 + cg * 32);
#pragma unroll
        for (int j = 0; j < 8; ++j) { wa[j] = pa[j]; wb[j] = pb[j]; }
    }

    // ---- serial recurrence: 2 __syncthreads per step, no global traffic ----
    for (int t = 0; t < SEQ; ++t) {
        const float4* hp = (const float4*)(hcur + cg * 32);   // broadcast
        float a0 = 0.f, a1 = 0.f;
#pragma unroll
        for (int j = 0; j < 8; ++j) {
            float4 v = hp[j];
            a0 += wa[j].x * v.x + wa[j].y * v.y + wa[j].z * v.z + wa[j].w * v.w;
            a1 += wb[j].x * v.x + wb[j].y * v.y + wb[j].z * v.z + wb[j].w * v.w;
        }
        *(float2*)(partial + cg * 520 + r0) = make_float2(a0, a1);
        __syncthreads();
        if (tid < H1) {
            const int c = tid;
            float s[4];
#pragma unroll
            for (int g = 0; g < 4; ++g) {
                float acc = gxs[g * H1 + c][t];
#pragma unroll
                for (int q = 0; q < 4; ++q) acc += partial[q * 520 + g * H1 + c];
                s[g] = acc;
            }
            float cn = sigm(s[1]) * creg + sigm(s[0]) * tanhfast(s[2]);
            creg = cn;
            float hn = sigm(s[3]) * tanhfast(cn);
            comb[t * H2 + dir * H1 + c] = hn;
            hcur[c] = hn;
        }
        __syncthreads();
    }
}

// ---------------------------------------------------------------------------
// Layer-2 LSTM: 4 blocks x 1024 threads. Block owns 64 cells (256 gate
// rows). Thread = (cg 0..7 [32 cols], row-pair rp 0..127) -> 64 w-floats.
// Cross-block h exchange via store-release flag + acquire-poll (no RMW
// barrier); polling waves overlap the gate-compute wave.
// ---------------------------------------------------------------------------
__global__ __launch_bounds__(1024, 4) void k_l2(
    const float* __restrict__ Whhl,
    const float* __restrict__ h0l, const float* __restrict__ c0l,
    const float* __restrict__ Wihl,
    const float* __restrict__ bihl, const float* __restrict__ bhhl,
    const float* __restrict__ comb,
    float* __restrict__ fb,        // [SEQ][H2]
    float* __restrict__ hg2,       // [H2] agent-scope exchange
    int* __restrict__ flags)       // flags[4], zeroed before launch
{
    const int b = blockIdx.x;                 // 0..3, cells [b*64, b*64+64)
    __shared__ float cs[SEQ * H2];            // 20480 B
    __shared__ float hcur[H2];                //  1024 B
    __shared__ float biasL[H2];               //  1024 B
    __shared__ float gxs[H2][SEQ + 1];        // 21504 B
    __shared__ float partial[8 * 260];        //  8320 B

    const int tid = threadIdx.x;
    const int cg  = tid >> 7;                 // 0..7 (32-col group), wave-uniform
    const int rp  = tid & 127;                // row pair
    const int L0  = rp * 2;                   // local rows L0, L0+1 (0..255)
    // global gate row for local row L: (L>>6)*H2 + b*64 + (L&63); L0 even ->
    // both rows are in the same gate block, R1 = R0 + 1.
    const int R0  = (L0 >> 6) * H2 + b * 64 + (L0 & 63);

    for (int i = tid; i < SEQ * H2; i += 1024) cs[i] = comb[i];
    if (tid < H2) {
        int g = tid >> 6, c = tid & 63;
        int R = g * H2 + b * 64 + c;
        biasL[tid] = bihl[R] + bhhl[R];
        hcur[tid]  = h0l[tid];
    }
    float creg = (tid < 64) ? c0l[b * 64 + tid] : 0.0f;

    float4 wa[8], wb[8];
    {
        const float4* pa = (const float4*)(Wihl + (size_t)R0 * H2 + cg * 32);
        const float4* pb = (const float4*)(Wihl + (size_t)(R0 + 1) * H2 + cg * 32);
#pragma unroll
        for (int j = 0; j < 8; ++j) { wa[j] = pa[j]; wb[j] = pb[j]; }
    }
    __syncthreads();

    // ---- prologue: gxs[L][t] = bias[L] + Wihl[R(L)]·comb[t] ----
    for (int t = 0; t < SEQ; ++t) {
        const float4* cp = (const float4*)(cs + t * H2 + cg * 32);
        float a0 = 0.f, a1 = 0.f;
#pragma unroll
        for (int j = 0; j < 8; ++j) {
            float4 v = cp[j];
            a0 += wa[j].x * v.x + wa[j].y * v.y + wa[j].z * v.z + wa[j].w * v.w;
            a1 += wb[j].x * v.x + wb[j].y * v.y + wb[j].z * v.z + wb[j].w * v.w;
        }
        *(float2*)(partial + cg * 260 + L0) = make_float2(a0, a1);
        __syncthreads();
        if (tid < H2) {
            float s = biasL[tid];
#pragma unroll
            for (int q = 0; q < 8; ++q) s += partial[q * 260 + tid];
            gxs[tid][t] = s;
        }
        __syncthreads();
    }

    // Whhl slice -> registers
    {
        const float4* pa = (const float4*)(Whhl + (size_t)R0 * H2 + cg * 32);
        const float4* pb = (const float4*)(Whhl + (size_t)(R0 + 1) * H2 + cg * 32);
#pragma unroll
        for (int j = 0; j < 8; ++j) { wa[j] = pa[j]; wb[j] = pb[j]; }
    }

    // ---- serial recurrence: 2 syncs/step; exchange overlapped with gates ----
    for (int t = 0; t < SEQ; ++t) {
        const float4* hp = (const float4*)(hcur + cg * 32);   // broadcast
        float a0 = 0.f, a1 = 0.f;
#pragma unroll
        for (int j = 0; j < 8; ++j) {
            float4 v = hp[j];
            a0 += wa[j].x * v.x + wa[j].y * v.y + wa[j].z * v.z + wa[j].w * v.w;
            a1 += wb[j].x * v.x + wb[j].y * v.y + wb[j].z * v.z + wb[j].w * v.w;
        }
        *(float2*)(partial + cg * 260 + L0) = make_float2(a0, a1);
        __syncthreads();

        if (tid < 64) {
            // gate wave: finish own 64 cells
            const int c = tid;
            float s[4];
#pragma unroll
            for (int g = 0; g < 4; ++g) {
                float acc = gxs[g * 64 + c][t];
#pragma unroll
                for (int q = 0; q < 8; ++q) acc += partial[q * 260 + g * 64 + c];
                s[g] = acc;
            }
            float cn = sigm(s[1]) * creg + sigm(s[0]) * tanhfast(s[2]);
            creg = cn;
            float hn = sigm(s[3]) * tanhfast(cn);
            fb[t * H2 + b * 64 + c] = hn;
            hcur[b * 64 + c] = hn;
            if (t + 1 < SEQ) {
                __hip_atomic_store(&hg2[b * 64 + c], hn,
                                   __ATOMIC_RELAXED, __HIP_MEMORY_SCOPE_AGENT);
                __threadfence();
                if (tid == 0)
                    __hip_atomic_store(&flags[b], t + 1,
                                       __ATOMIC_RELEASE, __HIP_MEMORY_SCOPE_AGENT);
            }
        } else if (tid < 256 && t + 1 < SEQ) {
            // loader waves: pull the 192 remote h values (per-wave uniform flag)
            const int idx = (b * 64 + tid) & 255;   // tid-64 -> offsets 64..255
            const int sh  = idx >> 6;
            while (__hip_atomic_load(&flags[sh], __ATOMIC_ACQUIRE,
                                     __HIP_MEMORY_SCOPE_AGENT) <= t)
                __builtin_amdgcn_s_sleep(1);
            hcur[idx] = __hip_atomic_load(&hg2[idx],
                                          __ATOMIC_RELAXED, __HIP_MEMORY_SCOPE_AGENT);
        }
        __syncthreads();
    }
}

// ---------------------------------------------------------------------------
// Output linear (unchanged). Thread = one class; fb transposed in LDS.
// ---------------------------------------------------------------------------
__global__ __launch_bounds__(256, 4) void k_out_v(
    const float* __restrict__ Wlin, const float* __restrict__ blin,
    const float* __restrict__ fb, float* __restrict__ out)
{
    __shared__ float fbs[H2][SEQ];
    const int tid = threadIdx.x;
    for (int t = 0; t < SEQ; ++t) fbs[tid][t] = fb[t * H2 + tid];
    __syncthreads();

    int n = blockIdx.x * 256 + tid;
    if (n >= NCLS) return;
    float acc[SEQ];
    float bv = blin[n];
#pragma unroll
    for (int t = 0; t < SEQ; ++t) acc[t] = bv;

    const float* wp = Wlin + (size_t)n * H2;
    for (int k = 0; k < H2; k += 4) {
        float4 wv = *(const float4*)(wp + k);
#pragma unroll
        for (int t = 0; t < SEQ; t += 4) {
            float4 f0 = *(const float4*)(&fbs[k][t]);
            float4 f1 = *(const float4*)(&fbs[k + 1][t]);
            float4 f2 = *(const float4*)(&fbs[k + 2][t]);
            float4 f3 = *(const float4*)(&fbs[k + 3][t]);
            acc[t]     += wv.x * f0.x + wv.y * f1.x + wv.z * f2.x + wv.w * f3.x;
            acc[t + 1] += wv.x * f0.y + wv.y * f1.y + wv.z * f2.y + wv.w * f3.y;
            acc[t + 2] += wv.x * f0.z + wv.y * f1.z + wv.z * f2.z + wv.w * f3.z;
            acc[t + 3] += wv.x * f0.w + wv.y * f1.w + wv.z * f2.w + wv.w * f3.w;
        }
    }
#pragma unroll
    for (int t = 0; t < SEQ; ++t)
        out[(size_t)t * NCLS + n] = acc[t];
}

// ---------------------------------------------------------------------------
extern "C" void kernel_launch(void* const* d_in, const int* in_sizes, int n_in,
                              void* d_out, int out_size, void* d_ws, size_t ws_size,
                              hipStream_t stream)
{
    const float* x    = (const float*)d_in[0];
    const float* h0f_ = (const float*)d_in[1];
    const float* c0f_ = (const float*)d_in[2];
    const float* h0b_ = (const float*)d_in[3];
    const float* c0b_ = (const float*)d_in[4];
    const float* h0l_ = (const float*)d_in[5];
    const float* c0l_ = (const float*)d_in[6];
    const float* WihF = (const float*)d_in[7];
    const float* WhhF = (const float*)d_in[8];
    const float* bihF = (const float*)d_in[9];
    const float* bhhF = (const float*)d_in[10];
    const float* WihB = (const float*)d_in[11];
    const float* WhhB = (const float*)d_in[12];
    const float* bihB = (const float*)d_in[13];
    const float* bhhB = (const float*)d_in[14];
    const float* Wihl = (const float*)d_in[15];
    const float* Whhl = (const float*)d_in[16];
    const float* bihl = (const float*)d_in[17];
    const float* bhhl = (const float*)d_in[18];
    const float* Wlin = (const float*)d_in[19];
    const float* blin = (const float*)d_in[20];

    char* ws = (char*)d_ws;
    int*   flags = (int*)ws;                     // 4 ints (256 B reserved)
    float* hg2   = (float*)(ws + 1536);          // [256]
    float* comb  = (float*)(ws + 4096);          // [20][256]
    float* fb    = (float*)(ws + 24576);         // [20][256]

    hipMemsetAsync(flags, 0, 256, stream);

    k_l1<<<2, 1024, 0, stream>>>(x, h0f_, c0f_, h0b_, c0b_,
                                 WihF, WhhF, bihF, bhhF,
                                 WihB, WhhB, bihB, bhhB,
                                 comb);
    k_l2<<<4, 1024, 0, stream>>>(Whhl, h0l_, c0l_,
                                 Wihl, bihl, bhhl,
                                 comb, fb, hg2, flags);
    k_out_v<<<391, 256, 0, stream>>>(Wlin, blin, fb, (float*)d_out);
}